// Round 9
// baseline (1854.639 us; speedup 1.0000x reference)
//
#include <hip/hip_runtime.h>
#include <math.h>

// Elman RNN, two-phase.
//   Phase 1 (parallel): z = x*W1^T + b1 + b2, f32-exact (3-product hi/lo
//     bf16 MFMA), stored INTO the h_seq region of d_out in an 8-ROW-ALIGNED
//     fragment layout: z(s, t8) occupies exactly the 4KB that h_seq(s, rows
//     8*t8..8*t8+8) later overwrites.
//     R8 LESSON: the previous 16-row slab interleaved two blocks' z rows in
//     one 8KB region -> (a) odd blocks indexed the wrong rows, (b) one
//     block's h_seq stores could clobber the other's unread z (unsynced
//     blocks). 8-row alignment makes every block's z reads and h_seq writes
//     the SAME disjoint byte range -> no cross-block hazard by construction.
//   Phase 2 (serial, 64 blocks x 4 waves): h_t = tanh(h_{t-1}*W2^T + z_t).
//     M=8 rows/block, N=32 units/wave: A-frag read once per wave reused for
//     2 N-subtiles (32 ds_read_b128/CU/step), LDS writes 8 rows only, per-CU
//     HBM 8KB/step, 64 CUs active. MFMA = dominant pipe (24/wave/step).
//     R5 LESSON: per-step h error must stay ~1e-6 (amplification ~3000x) ->
//     trunc hi/lo splits + 3 products: W2hi*h_hi + W2lo*h_hi + W2hi*h_lo.
//     One raw s_barrier+lgkmcnt per step; z(s) read (2 steps early) always
//     completes (vmcnt-drained by MFMA use) before h_seq(s) store issues.

#define S_LEN 2048
#define B_SZ  512
#define I_SZ  64
#define H_SZ  128
#define NTILE 32                   // 16-row prepass slabs
#define BLK1  512
#define BLK2  256                  // 4 waves
#define SPB   8                    // prepass: steps per block
#define SBH   (B_SZ * H_SZ)        // floats per step-slab in out

typedef short bf16x8 __attribute__((ext_vector_type(8)));
typedef float f32x4  __attribute__((ext_vector_type(4)));

#define MFMA(A, B, C) __builtin_amdgcn_mfma_f32_16x16x32_bf16((A), (B), (C), 0, 0, 0)

#define LDS_BARRIER()                                        \
    asm volatile("s_waitcnt lgkmcnt(0)" ::: "memory");       \
    __builtin_amdgcn_s_barrier();                            \
    asm volatile("" ::: "memory")

__device__ __forceinline__ unsigned fbits(float v) {
    union { float f; unsigned u; } x; x.f = v; return x.u;
}
__device__ __forceinline__ float fval(unsigned u) {
    union { float f; unsigned u; } x; x.u = u; return x.f;
}
__device__ __forceinline__ unsigned short bf_trunc(float v) {
    return (unsigned short)(fbits(v) >> 16);
}
// split 8 consecutive floats into hi/lo bf16 fragments (trunc, r4-proven)
__device__ __forceinline__ void split8t(float4 a, float4 b, bf16x8* hi, bf16x8* lo) {
    float v[8] = {a.x, a.y, a.z, a.w, b.x, b.y, b.z, b.w};
    #pragma unroll
    for (int j = 0; j < 8; ++j) {
        unsigned short h = bf_trunc(v[j]);
        (*hi)[j] = (short)h;
        (*lo)[j] = (short)bf_trunc(v[j] - fval(((unsigned)h) << 16));
    }
}

// ---------------- Phase 1: z = x*W1^T + b1 + b2 ----------------------------
// Store layout (floats, within slab (s,tile) of 2048 = bytes of h_seq rows
// 16*tile..+16): half(row>>3)*1024 + w*128 + ((row>>2)&1)*64 + col*4 + (row&3)
__global__ __launch_bounds__(BLK1) void rnn_prepass(
    const float* __restrict__ x,
    const float* __restrict__ W1,
    const float* __restrict__ b1,
    const float* __restrict__ b2,
    float* __restrict__ z)
{
    const int tid  = threadIdx.x;
    const int lane = tid & 63;
    const int w    = tid >> 6;
    const int l15  = lane & 15;
    const int l4   = lane >> 4;
    const int unit = (w << 4) + l15;
    const int bid  = blockIdx.x;
    const int tile = bid & (NTILE - 1);
    const int s0   = (bid >> 5) * SPB;
    const int b0   = tile << 4;

    bf16x8 w1h[2], w1l[2];
    #pragma unroll
    for (int c = 0; c < 2; ++c) {
        const float* wr = W1 + unit * I_SZ + 32 * c + l4 * 8;
        split8t(*(const float4*)wr, *(const float4*)(wr + 4), &w1h[c], &w1l[c]);
    }
    const float zb = b1[unit] + b2[unit];

    // C rows = 4*l4 + r: half = l4>>1, group = l4&1
    float* zo = z + (size_t)(s0 * NTILE + tile) * 2048 +
                (size_t)(l4 >> 1) * 1024 + w * 128 + (l4 & 1) * 64 + l15 * 4;

    for (int i = 0; i < SPB; ++i) {
        const int s = s0 + i;
        const float* xr = x + ((size_t)s * B_SZ + b0 + l15) * I_SZ + l4 * 8;
        bf16x8 xh[2], xl[2];
        #pragma unroll
        for (int c = 0; c < 2; ++c)
            split8t(*(const float4*)(xr + 32 * c), *(const float4*)(xr + 32 * c + 4),
                    &xh[c], &xl[c]);

        f32x4 acc  = {zb, zb, zb, zb};
        f32x4 acc2 = {0.f, 0.f, 0.f, 0.f};
        acc  = MFMA(xh[0], w1h[0], acc);   acc  = MFMA(xh[1], w1h[1], acc);
        acc2 = MFMA(xl[0], w1h[0], acc2);  acc2 = MFMA(xl[1], w1h[1], acc2);
        acc2 = MFMA(xh[0], w1l[0], acc2);  acc2 = MFMA(xh[1], w1l[1], acc2);
        acc += acc2;

        *(f32x4*)(zo + (size_t)i * (NTILE * 2048)) = acc;
    }
}

// ------- Phase 2: serial recurrence (64 blocks, M=8, 4 waves, N=32) -------
__global__ __launch_bounds__(BLK2, 1) void rnn_recur(
    const float* __restrict__ W2,
    const float* zr,              // z region (8-row fragment layout) == out
    float* out)
{
    const int tid  = threadIdx.x;
    const int lane = tid & 63;
    const int W    = tid >> 6;        // wave -> units [32W, 32W+32)
    const int l15  = lane & 15;
    const int l4   = lane >> 4;
    const int t8   = blockIdx.x;      // 8-row batch tile 0..63
    const int b0   = t8 << 3;         // first batch row

    __shared__ short hp_hi[2][8 * H_SZ];   // 2 x 2 KiB, XOR-swizzled
    __shared__ short hp_lo[2][8 * H_SZ];

    // W2 B-fragments hi/lo for the wave's two 16-unit subtiles
    bf16x8 w2h[2][4], w2l[2][4];
    #pragma unroll
    for (int st = 0; st < 2; ++st) {
        const int n = (W << 5) + (st << 4) + l15;
        #pragma unroll
        for (int c = 0; c < 4; ++c) {
            const float* wr = W2 + n * H_SZ + 32 * c + l4 * 8;
            split8t(*(const float4*)wr, *(const float4*)(wr + 4),
                    &w2h[st][c], &w2l[st][c]);
        }
    }

    // LDS offsets; swizzle: byte ^= row<<4 (rows 0..7, 256B rows)
    const int row8 = l15 & 7;              // A rows 8-15 duplicate 0-7
    int hro[4];
    #pragma unroll
    for (int c = 0; c < 4; ++c)
        hro[c] = row8 * 256 + ((64 * c + 16 * l4) ^ (row8 << 4));
    const int rwb = (l4 & 1) << 2;         // write rows (l4<2 only): rwb+r
    int woh[2][4];
    #pragma unroll
    for (int st = 0; st < 2; ++st)
        #pragma unroll
        for (int r = 0; r < 4; ++r) {
            int row = rwb + r;
            woh[st][r] = row * 256 +
                ((((W << 5) + (st << 4) + l15) * 2) ^ (row << 4));
        }
    const bool wmask = (l4 < 2);

    // z pointers: block's own 4KB region; C rows 4*(l4&1)+r, col l15
    const float* zp0 = zr + (size_t)b0 * H_SZ +
                       (size_t)(2 * W) * 128 + (l4 & 1) * 64 + l15 * 4;
    const float* zp1 = zp0 + 128;

    // h_seq pointers (standard layout): row b0+rwb+r, col 32W+16*st+l15
    float* po0 = out + (size_t)(b0 + rwb) * H_SZ + (W << 5) + l15;
    float* po1 = po0 + 16;

    // prologue: z(0), z(1) in flight; h0 = 0
    f32x4 zA0 = *(const f32x4*)(zp0);
    f32x4 zA1 = *(const f32x4*)(zp1);
    f32x4 zB0 = *(const f32x4*)(zp0 + SBH);
    f32x4 zB1 = *(const f32x4*)(zp1 + SBH);

    bf16x8 ah[4], al[4];
    #pragma unroll
    for (int c = 0; c < 4; ++c) { ah[c] = (bf16x8){0,0,0,0,0,0,0,0}; al[c] = ah[c]; }
    float tl0[4], tl1[4];

#define BODY(S, P, Z0, Z1)                                                    \
{                                                                             \
    f32x4 a0 = Z0, a1 = Z1;                                                   \
    f32x4 b0v = {0.f,0.f,0.f,0.f}, b1v = b0v, c0v = b0v, c1v = b0v;           \
    { int sp = (S) + 2; if (sp > S_LEN - 1) sp = S_LEN - 1;                   \
      Z0 = *(const f32x4*)(zp0 + (size_t)sp * SBH);                           \
      Z1 = *(const f32x4*)(zp1 + (size_t)sp * SBH); }                         \
    _Pragma("unroll")                                                         \
    for (int c = 0; c < 4; ++c) {                                             \
        a0  = MFMA(ah[c], w2h[0][c], a0);   a1  = MFMA(ah[c], w2h[1][c], a1); \
        b0v = MFMA(al[c], w2h[0][c], b0v);  b1v = MFMA(al[c], w2h[1][c], b1v);\
        c0v = MFMA(ah[c], w2l[0][c], c0v);  c1v = MFMA(ah[c], w2l[1][c], c1v);\
    }                                                                         \
    a0 = (a0 + b0v) + c0v;  a1 = (a1 + b1v) + c1v;                            \
    _Pragma("unroll")                                                         \
    for (int r = 0; r < 4; ++r) {                                             \
        float u0 = 1.0f - 2.0f * __builtin_amdgcn_rcpf(1.0f + __expf(2.0f*a0[r])); \
        float u1 = 1.0f - 2.0f * __builtin_amdgcn_rcpf(1.0f + __expf(2.0f*a1[r])); \
        tl0[r] = u0;  tl1[r] = u1;                                            \
        if (wmask) {                                                          \
            unsigned short h0 = bf_trunc(u0), h1 = bf_trunc(u1);              \
            *(short*)((char*)hp_hi[P] + woh[0][r]) = (short)h0;               \
            *(short*)((char*)hp_lo[P] + woh[0][r]) =                          \
                (short)bf_trunc(u0 - fval(((unsigned)h0) << 16));             \
            *(short*)((char*)hp_hi[P] + woh[1][r]) = (short)h1;               \
            *(short*)((char*)hp_lo[P] + woh[1][r]) =                          \
                (short)bf_trunc(u1 - fval(((unsigned)h1) << 16));             \
        }                                                                     \
    }                                                                         \
    LDS_BARRIER();                                                            \
    _Pragma("unroll")                                                         \
    for (int c = 0; c < 4; ++c) {                                             \
        ah[c] = *(const bf16x8*)((const char*)hp_hi[P] + hro[c]);             \
        al[c] = *(const bf16x8*)((const char*)hp_lo[P] + hro[c]);             \
    }                                                                         \
    /* h_seq stores AFTER the barrier: overlap next step's ds_read latency */ \
    if (wmask) {                                                              \
        _Pragma("unroll")                                                     \
        for (int r = 0; r < 4; ++r) {                                         \
            po0[(size_t)(S) * SBH + (size_t)r * H_SZ] = tl0[r];               \
            po1[(size_t)(S) * SBH + (size_t)r * H_SZ] = tl1[r];               \
        }                                                                     \
    }                                                                         \
}

    for (int s2 = 0; s2 < S_LEN; s2 += 2) {
        BODY(s2,     0, zA0, zA1);
        BODY(s2 + 1, 1, zB0, zB1);
    }
#undef BODY

    // h_last (step S_LEN-1 values held in tl)
    if (wmask) {
        #pragma unroll
        for (int r = 0; r < 4; ++r) {
            po0[(size_t)S_LEN * SBH + (size_t)r * H_SZ] = tl0[r];
            po1[(size_t)S_LEN * SBH + (size_t)r * H_SZ] = tl1[r];
        }
    }
}

extern "C" void kernel_launch(void* const* d_in, const int* in_sizes, int n_in,
                              void* d_out, int out_size, void* d_ws, size_t ws_size,
                              hipStream_t stream) {
    const float* x  = (const float*)d_in[0];
    const float* W1 = (const float*)d_in[1];
    const float* b1 = (const float*)d_in[2];
    const float* W2 = (const float*)d_in[3];
    const float* b2 = (const float*)d_in[4];
    float* out = (float*)d_out;

    rnn_prepass<<<dim3((S_LEN / SPB) * NTILE), dim3(BLK1), 0, stream>>>(x, W1, b1, b2, out);
    rnn_recur<<<dim3(2 * NTILE), dim3(BLK2), 0, stream>>>(W2, out, out);
}